// Round 1
// baseline (489.201 us; speedup 1.0000x reference)
//
#include <hip/hip_runtime.h>
#include <hip/hip_bf16.h>
#include <math.h>

#define B_ 16
#define S_ 4096
#define E_ 1024
#define H_ 512

#define BM 256
#define BN 256
#define BK 64
#define NCHUNK (E_ / BK)  // 16

typedef short bf16x8 __attribute__((ext_vector_type(8)));
typedef unsigned short u16x8 __attribute__((ext_vector_type(8)));
typedef float f32x4 __attribute__((ext_vector_type(4)));

__device__ inline unsigned short f2bf(float x) {
    __hip_bfloat16 h = __float2bfloat16(x);
    return *(unsigned short*)&h;
}
__device__ inline float bf2f(unsigned short u) {
    unsigned int x = ((unsigned int)u) << 16;
    float f;
    __builtin_memcpy(&f, &x, 4);
    return f;
}

#define GLD16(g, l_) __builtin_amdgcn_global_load_lds(                     \
    (const __attribute__((address_space(1))) void*)(g),                    \
    (__attribute__((address_space(3))) void*)(l_), 16, 0, 0)

#define BAR() do { asm volatile("" ::: "memory");                          \
                   __builtin_amdgcn_s_barrier();                           \
                   asm volatile("" ::: "memory"); } while (0)

// One launch, three jobs:
//  blocks 0..63    : We -> WeTcB bf16, swizzled-chunk layout:
//                    WeTcB[c*32768 + n*64 + cp*8 + j] = We[k][n],
//                    k = c*64 + (cp ^ (n&7))*8 + j   (bank-conflict-free frags)
//  blocks 64..191  : dp[b][h] = dec[b,:].Wd[:,h] + bd[h] + be[h]
//  blocks 192..    : enc fp32 -> encB bf16 (row-major), 16 elems/thread
__global__ __launch_bounds__(256) void prep_conv_kernel(
    const float* __restrict__ enc, const float* __restrict__ We,
    const float* __restrict__ dec, const float* __restrict__ Wd,
    const float* __restrict__ bd, const float* __restrict__ be,
    unsigned short* __restrict__ WeTcB, float* __restrict__ dp,
    unsigned short* __restrict__ encB) {
    __shared__ float red[4][64];
    int bid = blockIdx.x, t = threadIdx.x;
    if (bid < 64) {
        int c = bid >> 2, n0t = (bid & 3) * 128;
#pragma unroll 4
        for (int it = 0; it < 32; ++it) {
            int o = it * 256 + t;
            int n_rel = o >> 6, within = o & 63;
            int cp = within >> 3, j = within & 7;
            int n = n0t + n_rel;
            int k = c * 64 + ((cp ^ (n & 7)) << 3) + j;
            WeTcB[c * 32768 + n * 64 + within] = f2bf(We[(size_t)k * H_ + n]);
        }
    } else if (bid < 192) {
        int id = bid - 64;
        int b = id >> 3, hc = id & 7;
        int h = hc * 64 + (t & 63);
        int ec = t >> 6;
        const float* dr = dec + b * E_ + ec * 256;
        const float* wp = Wd + (size_t)(ec * 256) * H_ + h;
        float acc = 0.f;
#pragma unroll 8
        for (int e = 0; e < 256; ++e) acc = fmaf(dr[e], wp[(size_t)e * H_], acc);
        red[ec][t & 63] = acc;
        __syncthreads();
        if (t < 64) {
            int hh = hc * 64 + t;
            dp[b * H_ + hh] = red[0][t] + red[1][t] + red[2][t] + red[3][t] + bd[hh] + be[hh];
        }
    } else {
        size_t base = ((size_t)(bid - 192) * 256 + t) * 16;
        const float* ep = enc + base;
        unsigned short* op = encB + base;
        float4 v0 = *(const float4*)(ep);
        float4 v1 = *(const float4*)(ep + 4);
        float4 v2 = *(const float4*)(ep + 8);
        float4 v3 = *(const float4*)(ep + 12);
        u16x8 u0, u1;
        u0[0] = f2bf(v0.x); u0[1] = f2bf(v0.y); u0[2] = f2bf(v0.z); u0[3] = f2bf(v0.w);
        u0[4] = f2bf(v1.x); u0[5] = f2bf(v1.y); u0[6] = f2bf(v1.z); u0[7] = f2bf(v1.w);
        u1[0] = f2bf(v2.x); u1[1] = f2bf(v2.y); u1[2] = f2bf(v2.z); u1[3] = f2bf(v2.w);
        u1[4] = f2bf(v3.x); u1[5] = f2bf(v3.y); u1[6] = f2bf(v3.z); u1[7] = f2bf(v3.w);
        *(u16x8*)(op) = u0;
        *(u16x8*)(op + 8) = u1;
    }
}

// 256x256x64 8-phase GEMM (T2+T3+T4+T5):
//   8 waves (2M x 4N), per-wave C = 128x64 = acc[8][4] f32x4.
//   LDS: 2 x (A 32K + B 32K) double-buffer = 128 KiB, + sRed 4 KiB.
//   Per K-tile, 4 phases (quadrants m0n0, m0n1, m1n0, m1n1), 16 MFMA each.
//   Staging (global_load_lds 16B, pre-swizzled global source -> linear LDS,
//   XOR (row&7) on ds_read side): ph1 stages (t+1) B-h1; ph3 stages (t+2) B-h0;
//   ph4 stages (t+2) A-h0+h1.  Each stage lands >=1 barrier after the last
//   ds_read of the region it overwrites.  Counted s_waitcnt vmcnt(6) ONLY at
//   tile boundaries (3 half-tiles stay in flight across barriers); vmcnt(0)
//   once, entering the last tile.  s_setprio(1) around each MFMA cluster.
//   Epilogue: tanh(acc + dp) * Wo, h-reduce -> parts[nt][b][s], nt in {0,1}.
__global__ __launch_bounds__(512, 2) void scores_gemm_kernel(
    const unsigned short* __restrict__ encB, const unsigned short* __restrict__ WeTcB,
    const float* __restrict__ Wo, const float* __restrict__ dp,
    float* __restrict__ parts) {
    __shared__ unsigned short sA[2][BM * BK];  // 2 x 32 KB
    __shared__ unsigned short sB[2][BN * BK];  // 2 x 32 KB
    __shared__ float sRed[4][BM];              // 4 KB

    int tid = threadIdx.x;
    int w8 = tid >> 6, l = tid & 63;
    int l16 = l & 15, quad = l >> 4;
    int wm = w8 >> 2, wn = w8 & 3;
    int lrow = l >> 3, lcp = l & 7;

    int bid = blockIdx.x;
    int xcd = bid & 7;
    int sq = bid >> 3;
    int nt = sq & 1;                       // 2 nt-siblings share an XCD (bid%8)
    int mt = ((sq >> 1) << 3) + xcd;       // [0,256)
    size_t m0 = (size_t)mt * BM;
    int n0 = nt * BN;
    int b = mt >> 4;

    // staging lane constants: lane gathers logical k-chunk (lcp ^ lrow) so the
    // linear LDS write leaves logical chunk q at phys q ^ (row&7).
    const unsigned short* gA_base = encB + (m0 + (size_t)(w8 * 8 + lrow)) * E_ + (lcp ^ lrow) * 8;
    const unsigned short* gB_base = WeTcB + (size_t)(n0 + w8 * 8) * BK + l * 8;

#define STAGE_A(bb, tt, hh) do {                                               \
        const unsigned short* _s = gA_base + (size_t)((hh) * 128) * E_ + (tt) * BK; \
        GLD16(_s, &sA[bb][((hh) * 128 + w8 * 8) * BK]);                        \
        GLD16(_s + (size_t)64 * E_, &sA[bb][((hh) * 128 + 64 + w8 * 8) * BK]); \
    } while (0)
#define STAGE_B(bb, tt, hh) do {                                               \
        const unsigned short* _s = gB_base + (size_t)(tt) * (H_ * BK) + (hh) * 128 * BK; \
        GLD16(_s, &sB[bb][((hh) * 128 + w8 * 8) * BK]);                        \
        GLD16(_s + 64 * BK, &sB[bb][((hh) * 128 + 64 + w8 * 8) * BK]);         \
    } while (0)

    f32x4 acc[8][4];
#pragma unroll
    for (int i = 0; i < 8; ++i)
#pragma unroll
        for (int j = 0; j < 4; ++j) acc[i][j] = (f32x4)0.f;

    int aOff = (wm * 128 + l16) * BK;
    int bOff = (wn * 64 + l16) * BK;
    int sw = l16 & 7;
    int kq0 = ((quad ^ sw) << 3);
    int kq1 = (((4 + quad) ^ sw) << 3);

    // Prologue: tile0 fully + tile1 {B-h0, A-h0, A-h1}; wait tile0 (6 in flight).
    STAGE_A(0, 0, 0); STAGE_A(0, 0, 1); STAGE_B(0, 0, 0); STAGE_B(0, 0, 1);
    STAGE_B(1, 1, 0); STAGE_A(1, 1, 0); STAGE_A(1, 1, 1);
    asm volatile("s_waitcnt vmcnt(6)" ::: "memory");
    BAR();

    for (int t = 0; t < NCHUNK; ++t) {
        int cur = t & 1, nxt = cur ^ 1;
        const unsigned short* sAc = sA[cur];
        const unsigned short* sBc = sB[cur];
        bf16x8 aF[4][2], bF[4][2];

        // ---- phase 1: read A im0-3, B jn0-1; stage (t+1) B-h1 ----
#pragma unroll
        for (int im = 0; im < 4; ++im) {
            aF[im][0] = *(const bf16x8*)(sAc + aOff + im * 1024 + kq0);
            aF[im][1] = *(const bf16x8*)(sAc + aOff + im * 1024 + kq1);
        }
#pragma unroll
        for (int jn = 0; jn < 2; ++jn) {
            bF[jn][0] = *(const bf16x8*)(sBc + bOff + jn * 1024 + kq0);
            bF[jn][1] = *(const bf16x8*)(sBc + bOff + jn * 1024 + kq1);
        }
        if (t + 1 < NCHUNK) STAGE_B(nxt, t + 1, 1);
        BAR();
        __builtin_amdgcn_s_setprio(1);
#pragma unroll
        for (int ks = 0; ks < 2; ++ks)
#pragma unroll
            for (int im = 0; im < 4; ++im)
#pragma unroll
                for (int jn = 0; jn < 2; ++jn)
                    acc[im][jn] = __builtin_amdgcn_mfma_f32_16x16x32_bf16(
                        aF[im][ks], bF[jn][ks], acc[im][jn], 0, 0, 0);
        __builtin_amdgcn_s_setprio(0);
        BAR();

        // ---- phase 2: read B jn2-3 ----
#pragma unroll
        for (int jn = 0; jn < 2; ++jn) {
            bF[2 + jn][0] = *(const bf16x8*)(sBc + bOff + (2 + jn) * 1024 + kq0);
            bF[2 + jn][1] = *(const bf16x8*)(sBc + bOff + (2 + jn) * 1024 + kq1);
        }
        BAR();
        __builtin_amdgcn_s_setprio(1);
#pragma unroll
        for (int ks = 0; ks < 2; ++ks)
#pragma unroll
            for (int im = 0; im < 4; ++im)
#pragma unroll
                for (int jn = 0; jn < 2; ++jn)
                    acc[im][2 + jn] = __builtin_amdgcn_mfma_f32_16x16x32_bf16(
                        aF[im][ks], bF[2 + jn][ks], acc[im][2 + jn], 0, 0, 0);
        __builtin_amdgcn_s_setprio(0);
        BAR();

        // ---- phase 3: read A im4-7; stage (t+2) B-h0 (B of cur last read ph2) ----
#pragma unroll
        for (int im = 0; im < 4; ++im) {
            aF[im][0] = *(const bf16x8*)(sAc + aOff + (4 + im) * 1024 + kq0);
            aF[im][1] = *(const bf16x8*)(sAc + aOff + (4 + im) * 1024 + kq1);
        }
        if (t + 2 < NCHUNK) STAGE_B(cur, t + 2, 0);
        BAR();
        __builtin_amdgcn_s_setprio(1);
#pragma unroll
        for (int ks = 0; ks < 2; ++ks)
#pragma unroll
            for (int im = 0; im < 4; ++im)
#pragma unroll
                for (int jn = 0; jn < 2; ++jn)
                    acc[4 + im][jn] = __builtin_amdgcn_mfma_f32_16x16x32_bf16(
                        aF[im][ks], bF[jn][ks], acc[4 + im][jn], 0, 0, 0);
        __builtin_amdgcn_s_setprio(0);
        BAR();

        // ---- phase 4: stage (t+2) A-h0+h1 (A of cur last read ph3); MFMA m1n1 ----
        if (t + 2 < NCHUNK) { STAGE_A(cur, t + 2, 0); STAGE_A(cur, t + 2, 1); }
        __builtin_amdgcn_s_setprio(1);
#pragma unroll
        for (int ks = 0; ks < 2; ++ks)
#pragma unroll
            for (int im = 0; im < 4; ++im)
#pragma unroll
                for (int jn = 0; jn < 2; ++jn)
                    acc[4 + im][2 + jn] = __builtin_amdgcn_mfma_f32_16x16x32_bf16(
                        aF[im][ks], bF[2 + jn][ks], acc[4 + im][2 + jn], 0, 0, 0);
        __builtin_amdgcn_s_setprio(0);
        if (t < NCHUNK - 2) {
            asm volatile("s_waitcnt vmcnt(6)" ::: "memory");  // (t+1) landed; 3 half-tiles in flight
        } else if (t == NCHUNK - 2) {
            asm volatile("s_waitcnt vmcnt(0)" ::: "memory");  // drain for last tile
        }
        if (t < NCHUNK - 1) BAR();
    }
#undef STAGE_A
#undef STAGE_B

    // Epilogue: tanh(acc + dp) * Wo, partial reduce over this block's 256 h.
    float dpv[4], wov[4];
    const float* dpb = dp + b * H_;
#pragma unroll
    for (int jn = 0; jn < 4; ++jn) {
        int h = n0 + wn * 64 + jn * 16 + l16;
        dpv[jn] = dpb[h];
        wov[jn] = Wo[h];
    }
#pragma unroll
    for (int im = 0; im < 8; ++im)
#pragma unroll
        for (int r = 0; r < 4; ++r) {
            float s = 0.f;
#pragma unroll
            for (int jn = 0; jn < 4; ++jn) {
                float x = acc[im][jn][r] + dpv[jn];
                float e = __expf(2.f * x);
                s += (1.f - 2.f / (e + 1.f)) * wov[jn];
            }
            s += __shfl_xor(s, 1, 64);
            s += __shfl_xor(s, 2, 64);
            s += __shfl_xor(s, 4, 64);
            s += __shfl_xor(s, 8, 64);
            if (l16 == 0) sRed[wn][wm * 128 + im * 16 + quad * 4 + r] = s;
        }
    __syncthreads();
    if (tid < BM) {
        int s_in = (int)(m0 & (S_ - 1)) + tid;
        parts[(size_t)(nt * B_ + b) * S_ + s_in] =
            sRed[0][tid] + sRed[1][tid] + sRed[2][tid] + sRed[3][tid];
    }
}

// Row softmax stats only: stats[b] = (max, sumexp) over summed 2-slab scores.
__global__ __launch_bounds__(256) void stats_kernel(const float* __restrict__ parts,
                                                    float2* __restrict__ stats) {
    int b = blockIdx.x, tid = threadIdx.x;
    const float4* p0 = (const float4*)(parts + (size_t)(0 * B_ + b) * S_);
    const float4* p1 = (const float4*)(parts + (size_t)(1 * B_ + b) * S_);
    float4 v[4];
    float m = -1e30f;
#pragma unroll
    for (int i = 0; i < 4; ++i) {
        int idx = i * 256 + tid;
        float4 a0 = p0[idx], a1 = p1[idx];
        v[i].x = a0.x + a1.x;
        v[i].y = a0.y + a1.y;
        v[i].z = a0.z + a1.z;
        v[i].w = a0.w + a1.w;
        m = fmaxf(m, fmaxf(fmaxf(v[i].x, v[i].y), fmaxf(v[i].z, v[i].w)));
    }
    for (int off = 32; off; off >>= 1) m = fmaxf(m, __shfl_xor(m, off, 64));
    __shared__ float redm[4];
    __shared__ float reds[4];
    if ((tid & 63) == 0) redm[tid >> 6] = m;
    __syncthreads();
    m = fmaxf(fmaxf(redm[0], redm[1]), fmaxf(redm[2], redm[3]));
    float s = 0.f;
#pragma unroll
    for (int i = 0; i < 4; ++i) {
        s += __expf(v[i].x - m) + __expf(v[i].y - m);
        s += __expf(v[i].z - m) + __expf(v[i].w - m);
    }
    for (int off = 32; off; off >>= 1) s += __shfl_xor(s, off, 64);
    if ((tid & 63) == 0) reds[tid >> 6] = s;
    __syncthreads();
    if (tid == 0) {
        stats[b] = make_float2(m, reds[0] + reds[1] + reds[2] + reds[3]);
    }
}

// ctx partials from bf16 enc copy, unnormalized weights exp(sc - m).
__global__ __launch_bounds__(256) void ctx_partial_bf16(
    const unsigned short* __restrict__ encB, const float* __restrict__ parts,
    const float2* __restrict__ stats, float* __restrict__ part) {
    int b = blockIdx.x >> 5;
    int c = blockIdx.x & 31;
    int s0 = c * 128;
    int tid = threadIdx.x;
    __shared__ float w[128];
    if (tid < 128) {
        size_t idx = (size_t)b * S_ + s0 + tid;
        float x = parts[idx] + parts[(size_t)B_ * S_ + idx];
        w[tid] = __expf(x - stats[b].x);
    }
    __syncthreads();
    int e8 = (tid & 127) * 8;
    int sh = tid >> 7;
    const unsigned short* base = encB + ((size_t)b * S_ + s0 + sh * 64) * E_ + e8;
    const float* wp = w + sh * 64;
    float acc[8];
#pragma unroll
    for (int t = 0; t < 8; ++t) acc[t] = 0.f;
    for (int s = 0; s < 64; s += 8) {
        u16x8 v[8];
#pragma unroll
        for (int u = 0; u < 8; ++u) v[u] = *(const u16x8*)(base + (size_t)(s + u) * E_);
#pragma unroll
        for (int u = 0; u < 8; ++u) {
            float ws = wp[s + u];
#pragma unroll
            for (int t = 0; t < 8; ++t) acc[t] = fmaf(ws, bf2f(v[u][t]), acc[t]);
        }
    }
    float* po = part + ((size_t)(b * 64 + c * 2 + sh)) * E_ + e8;
    *(float4*)(po) = make_float4(acc[0], acc[1], acc[2], acc[3]);
    *(float4*)(po + 4) = make_float4(acc[4], acc[5], acc[6], acc[7]);
}

__global__ __launch_bounds__(256) void ctx_reduce(const float* __restrict__ part,
                                                  const float2* __restrict__ stats,
                                                  float* __restrict__ out) {
    int idx = blockIdx.x * 256 + threadIdx.x;  // 16*1024
    int b = idx >> 10;
    int e = idx & 1023;
    const float* p = part + (size_t)b * 64 * E_ + e;
    float s0 = 0.f, s1 = 0.f, s2 = 0.f, s3 = 0.f;
    for (int c = 0; c < 64; c += 4) {
        s0 += p[(size_t)(c + 0) * E_];
        s1 += p[(size_t)(c + 1) * E_];
        s2 += p[(size_t)(c + 2) * E_];
        s3 += p[(size_t)(c + 3) * E_];
    }
    out[idx] = ((s0 + s1) + (s2 + s3)) * (1.f / stats[b].y);
}

extern "C" void kernel_launch(void* const* d_in, const int* in_sizes, int n_in,
                              void* d_out, int out_size, void* d_ws, size_t ws_size,
                              hipStream_t stream) {
    const float* enc = (const float*)d_in[0];  // [16,4096,1024]
    const float* dec = (const float*)d_in[1];  // [16,1024]
    const float* We  = (const float*)d_in[2];  // [1024,512]
    const float* be  = (const float*)d_in[3];  // [512]
    const float* Wd  = (const float*)d_in[4];  // [1024,512]
    const float* bd  = (const float*)d_in[5];  // [512]
    const float* Wo  = (const float*)d_in[6];  // [512,1]
    float* out = (float*)d_out;                // [16,1024]

    char* wsp = (char*)d_ws;
    unsigned short* WeTcB = (unsigned short*)wsp;              // 1 MiB
    float* dp = (float*)(wsp + (1 << 20));                     // 32 KiB
    float2* stats = (float2*)(wsp + (1 << 20) + (32 << 10));   // 128 B
    float* parts = (float*)(wsp + (1 << 20) + (64 << 10));     // 512 KiB (2 slabs)
    float* part = (float*)(wsp + (4 << 20));                   // 4 MiB
    unsigned short* encB = (unsigned short*)(wsp + (8 << 20)); // 128 MiB

    prep_conv_kernel<<<192 + 16384, 256, 0, stream>>>(enc, We, dec, Wd, bd, be,
                                                      WeTcB, dp, encB);
    scores_gemm_kernel<<<(B_ * S_ / BM) * (H_ / BN), 512, 0, stream>>>(
        encB, WeTcB, Wo, dp, parts);
    stats_kernel<<<B_, 256, 0, stream>>>(parts, stats);
    ctx_partial_bf16<<<B_ * 32, 256, 0, stream>>>(encB, parts, stats, part);
    ctx_reduce<<<B_ * E_ / 256, 256, 0, stream>>>(part, stats, out);
}